// Round 5
// baseline (1192.294 us; speedup 1.0000x reference)
//
#include <hip/hip_runtime.h>
#include <math.h>

#define Dn 256
#define Hn 64

typedef __attribute__((ext_vector_type(8))) short short8;
typedef float floatx4 __attribute__((ext_vector_type(4)));

static __device__ __forceinline__ unsigned short f2bf(float x) {
    unsigned int u = __float_as_uint(x);
    unsigned int r = (u + 0x7fffu + ((u >> 16) & 1u)) >> 16;   // RNE
    return (unsigned short)r;
}

// ---------------------------------------------------------------------------
// prep_all: fused prep.
//  blocks [0, 2048): masked bf16 weights in MFMA B-fragment layout.
//    Fragment (i,c,nb,lane,e) <-> kk = nb*16+(lane&15), j = c*32+(lane>>4)*8+e
//    Wb byte offset: i*32768 + (c*4+nb)*1024 + lane*16
//  blocks [2048, 2560): nsT[d*B + b] = exp(log_sigma[d]) * noise[b*Dn + d]
// ---------------------------------------------------------------------------
__global__ __launch_bounds__(256) void prep_all(const float* __restrict__ W1,
                                                const float* __restrict__ adj,
                                                const float* __restrict__ noise,
                                                const float* __restrict__ ls,
                                                unsigned short* __restrict__ Wb,
                                                float* __restrict__ nsT, int B) {
    const int bid = blockIdx.x;
    const int t = threadIdx.x;
    if (bid < 2048) {
        const int c = bid & 7, i = bid >> 3;
        const int nb = t >> 6, l = t & 63;
        const int kk = nb * 16 + (l & 15);
        const int jb = c * 32 + ((l >> 4) & 3) * 8;
        const float* wp = W1 + ((size_t)i * Hn + kk) * Dn + jb;
        unsigned short v[8];
#pragma unroll
        for (int e = 0; e < 8; ++e) {
            int j = jb + e;
            float m = 0.f;
            if (j != i) m = 1.f / (1.f + __expf(-adj[(size_t)j * Dn + i]));
            v[e] = f2bf(wp[e] * m);
        }
        unsigned short* dst = Wb + ((((size_t)i * 8 + c) * 4 + nb) * 64 + l) * 8;
        *(short8*)dst = *(const short8*)v;
    } else {
        __shared__ float tile[64][65];
        const int b2id = bid - 2048;
        const int bi = (b2id & 127) * 64, dj = (b2id >> 7) * 64;
        const int c = t & 63, rq = t >> 6;
#pragma unroll
        for (int it = 0; it < 16; ++it) {
            int b = bi + it * 4 + rq;
            tile[it * 4 + rq][c] = noise[(size_t)b * Dn + dj + c];
        }
        __syncthreads();
#pragma unroll
        for (int it = 0; it < 16; ++it) {
            int d = dj + it * 4 + rq;
            float sg = __expf(ls[d]);
            nsT[(size_t)d * B + bi + c] = tile[c][it * 4 + rq] * sg;
        }
    }
}

// ---------------------------------------------------------------------------
// scm_main: sequential SCM, group-ahead bulk structure.
// Block = 128 threads = 2 waves; wave w owns 16 rows x all 64 hidden.
// Per group g (8 steps, section sec=g>>2):
//   Phase 1: Hpre[8][4] (VGPR fp32 acc) = sum_{c<sec} af[c] x B[i][c]  — bulk,
//            deep-pipelined global->VGPR loads, no serial dependency.
//   Phase 2: 8 serial steps: acc = mfma(ain, Bcur, Hpre[ip]); silu-dot epilogue;
//            swizzle-reduce; insert z into ain.  Bcur + scalar params register-
//            prefetched 2 steps ahead.
// z history entirely in registers (af[7] frozen + ain in-progress). No LDS.
// One __syncthreads per group keeps the 2 waves lockstep for L1 dedup of the
// shared B stream (drain cost ~200cy/group, not per step).
// grid: B/32 = 256, block 128
// ---------------------------------------------------------------------------
__global__ __launch_bounds__(128, 1) void scm_main(const unsigned short* __restrict__ Wb,
                                                   const float* __restrict__ b1,
                                                   const float* __restrict__ W2,
                                                   const float* __restrict__ b2,
                                                   const float* __restrict__ nsT,
                                                   float* __restrict__ out, int B) {
    const int t = threadIdx.x;
    const int w = t >> 6, l = t & 63;
    const int n = l & 15, q = l >> 4;
    const int rowbase = blockIdx.x * 32 + w * 16;
    const unsigned char* wb_l = (const unsigned char*)Wb + (size_t)l * 16;

    short8 af[7];                  // frozen 32-col chunks of this lane's A-row
    short8 ain = (short8)0;        // in-progress chunk
#pragma unroll
    for (int c = 0; c < 7; ++c) af[c] = (short8)0;

    // 2-deep register prefetch ring for the serial phase (slot = step parity)
    short8 bpre[2][4];
    float b1p[2][4], w2p[2][4], b2p[2];
    float4 nvp[2];
#pragma unroll
    for (int s = 0; s < 2; ++s) {
        const unsigned char* src = wb_l + (size_t)s * 32768;   // steps 0,1: chunk 0
#pragma unroll
        for (int nb = 0; nb < 4; ++nb) {
            bpre[s][nb] = *(const short8*)(src + nb * 1024);
            b1p[s][nb]  = b1[s * Hn + nb * 16 + n];
            w2p[s][nb]  = W2[s * Hn + nb * 16 + n];
        }
        nvp[s] = *(const float4*)(nsT + (size_t)s * B + rowbase + q * 4);
        b2p[s] = b2[s];
    }

    float zout[8];

#pragma unroll 1
    for (int g = 0; g < 32; ++g) {
        const int sec = g >> 2;
        // section boundary: promote completed chunk into the frozen cache
        if ((g & 3) == 0 && g > 0) {
#pragma unroll
            for (int k2 = 0; k2 < 7; ++k2)
                if (sec - 1 == k2) af[k2] = ain;
            ain = (short8)0;
        }

        __syncthreads();   // keep both waves' B streams L1-coincident

        // ---- Phase 1: bulk history GEMM into Hpre (registers) ----
        floatx4 Hp[8][4];
        floatx4 zero4 = {0.f, 0.f, 0.f, 0.f};
#pragma unroll
        for (int ip = 0; ip < 8; ++ip)
#pragma unroll
            for (int nb = 0; nb < 4; ++nb) Hp[ip][nb] = zero4;

#pragma unroll
        for (int c = 0; c < 7; ++c)
            if (c < sec) {
#pragma unroll
                for (int ip = 0; ip < 8; ++ip) {
                    const unsigned char* src =
                        wb_l + (size_t)(g * 8 + ip) * 32768 + (size_t)c * 4096;
#pragma unroll
                    for (int nb = 0; nb < 4; ++nb) {
                        short8 bfr = *(const short8*)(src + nb * 1024);
                        Hp[ip][nb] = __builtin_amdgcn_mfma_f32_16x16x32_bf16(
                            af[c], bfr, Hp[ip][nb], 0, 0, 0);
                    }
                }
            }

        // ---- Phase 2: 8 serial steps ----
#pragma unroll
        for (int ip = 0; ip < 8; ++ip) {
            const int i = g * 8 + ip;
            const int s = ip & 1;             // slot parity (g*8 even)

            // consume prefetched step-i data
            short8 bc[4];
            float b1c[4], w2c[4], nvr[4];
            float b2c = b2p[s];
#pragma unroll
            for (int nb = 0; nb < 4; ++nb) {
                bc[nb]  = bpre[s][nb];
                b1c[nb] = b1p[s][nb];
                w2c[nb] = w2p[s][nb];
            }
            nvr[0] = nvp[s].x; nvr[1] = nvp[s].y; nvr[2] = nvp[s].z; nvr[3] = nvp[s].w;

            // prefetch step i+2 into the same slot
            {
                int it = i + 2; if (it > 255) it = 255;
                const int ci = it >> 5;
                const unsigned char* src =
                    wb_l + (size_t)it * 32768 + (size_t)ci * 4096;
#pragma unroll
                for (int nb = 0; nb < 4; ++nb) {
                    bpre[s][nb] = *(const short8*)(src + nb * 1024);
                    b1p[s][nb]  = b1[it * Hn + nb * 16 + n];
                    w2p[s][nb]  = W2[it * Hn + nb * 16 + n];
                }
                nvp[s] = *(const float4*)(nsT + (size_t)it * B + rowbase + q * 4);
                b2p[s] = b2[it];
            }

            // serial MFMAs: in-progress chunk on top of precomputed history
            floatx4 acc[4];
#pragma unroll
            for (int nb = 0; nb < 4; ++nb)
                acc[nb] = __builtin_amdgcn_mfma_f32_16x16x32_bf16(
                    ain, bc[nb], Hp[ip][nb], 0, 0, 0);

            // epilogue: silu(h) . W2 over this wave's 64 hidden
            float d[4];
#pragma unroll
            for (int r = 0; r < 4; ++r) {
                float ssum = 0.f;
#pragma unroll
                for (int nb = 0; nb < 4; ++nb) {
                    float h = acc[nb][r] + b1c[nb];
                    ssum += __fdividef(h, 1.f + __expf(-h)) * w2c[nb];
                }
                d[r] = ssum;
            }
            // reduce over the 16 n-lanes
#pragma unroll
            for (int m = 1; m <= 8; m <<= 1) {
#pragma unroll
                for (int r = 0; r < 4; ++r) d[r] += __shfl_xor(d[r], m);
            }
            float z[4];
#pragma unroll
            for (int r = 0; r < 4; ++r) z[r] = d[r] + b2c + nvr[r];

            // zrow = z of row n (this lane's A-row)
            int srcl = ((l & 15) >> 2) << 4;
            float t0 = __shfl(z[0], srcl), t1 = __shfl(z[1], srcl);
            float t2 = __shfl(z[2], srcl), t3 = __shfl(z[3], srcl);
            float za = (l & 1) ? t1 : t0;
            float zb = (l & 1) ? t3 : t2;
            float zrow = (l & 2) ? zb : za;

            // insert bf16(zrow) into ain at element ip, owner quad o = g&3
            unsigned short zb16 = f2bf(zrow);
            const int o = g & 3;
            if (q == o) ain[ip] = (short)zb16;

            zout[ip] = zrow;
        }

        // output: rows 0..15 of this wave from q==0 lanes, 2 float4 stores
        if (q == 0) {
            float* op = out + (size_t)(rowbase + n) * Dn + g * 8;
            *(float4*)op       = make_float4(zout[0], zout[1], zout[2], zout[3]);
            *(float4*)(op + 4) = make_float4(zout[4], zout[5], zout[6], zout[7]);
        }
    }
}

// ---------------------------------------------------------------------------
extern "C" void kernel_launch(void* const* d_in, const int* in_sizes, int n_in,
                              void* d_out, int out_size, void* d_ws, size_t ws_size,
                              hipStream_t stream) {
    const float* noise      = (const float*)d_in[0];
    const float* adj_logits = (const float*)d_in[1];
    const float* W1         = (const float*)d_in[2];
    const float* b1         = (const float*)d_in[3];
    const float* W2         = (const float*)d_in[4];
    const float* b2         = (const float*)d_in[5];
    const float* log_sigma  = (const float*)d_in[6];
    float* out = (float*)d_out;

    const int B = in_sizes[0] / Dn;                       // 8192
    unsigned short* Wb  = (unsigned short*)d_ws;          // 8.39 MB fragment weights
    float*          nsT = (float*)((char*)d_ws + (size_t)Dn * Dn * Hn * 2);

    prep_all<<<dim3(2048 + 512), 256, 0, stream>>>(W1, adj_logits, noise, log_sigma,
                                                   Wb, nsT, B);
    scm_main<<<dim3(B / 32), 128, 0, stream>>>(Wb, b1, W2, b2, nsT, out, B);
}

// Round 6
// 603.103 us; speedup vs baseline: 1.9769x; 1.9769x over previous
//
#include <hip/hip_runtime.h>
#include <math.h>

#define Dn 256
#define Hn 64

typedef __attribute__((ext_vector_type(8))) short short8;
typedef __attribute__((ext_vector_type(4))) short short4v;
typedef float floatx4 __attribute__((ext_vector_type(4)));

static __device__ __forceinline__ unsigned short f2bf(float x) {
    unsigned int u = __float_as_uint(x);
    unsigned int r = (u + 0x7fffu + ((u >> 16) & 1u)) >> 16;   // RNE
    return (unsigned short)r;
}

// async global->LDS, 16B/lane: HW writes lane's 16B at (uniform lds base + lane*16)
static __device__ __forceinline__ void dma16(const void* g, void* l) {
    __builtin_amdgcn_global_load_lds(
        (__attribute__((address_space(1))) void*)g,
        (__attribute__((address_space(3))) void*)l, 16, 0, 0);
}

// ---------------------------------------------------------------------------
// prep_wb: masked bf16 weights in MFMA B-fragment layout, one block per i.
// Coalesced global reads (float4 along j), transpose through LDS, coalesced
// short8 stores.  Fragment (i,c,nb,lane,e) <-> kk=nb*16+(lane&15),
// j=c*32+((lane>>4)&3)*8+e.  Wb byte off: i*32768 + (c*4+nb)*1024 + lane*16.
// grid 256, block 256
// ---------------------------------------------------------------------------
__global__ __launch_bounds__(256) void prep_wb(const float* __restrict__ W1,
                                               const float* __restrict__ adj,
                                               unsigned short* __restrict__ Wb) {
    __shared__ unsigned short tile[64][264];   // [k][j], padded stride
    __shared__ float sg[256];
    const int i = blockIdx.x;
    const int t = threadIdx.x;
    {
        float x = adj[(size_t)t * Dn + i];
        sg[t] = (t == i) ? 0.f : 1.f / (1.f + __expf(-x));
    }
    __syncthreads();
#pragma unroll
    for (int r = 0; r < 16; ++r) {
        int flat = r * 1024 + t * 4;           // k = flat>>8, j = flat&255
        int k = flat >> 8, j = flat & 255;
        float4 v = *(const float4*)(W1 + (size_t)i * 16384 + flat);
        float4 s = *(const float4*)&sg[j];
        short4v p;
        p.x = (short)f2bf(v.x * s.x); p.y = (short)f2bf(v.y * s.y);
        p.z = (short)f2bf(v.z * s.z); p.w = (short)f2bf(v.w * s.w);
        *(short4v*)&tile[k][j] = p;
    }
    __syncthreads();
#pragma unroll
    for (int rep = 0; rep < 8; ++rep) {
        int id = rep * 256 + t;
        int c = id >> 8, nb = (id >> 6) & 3, l = id & 63;
        int kk = nb * 16 + (l & 15);
        int jb = c * 32 + ((l >> 4) & 3) * 8;
        short8 v = *(const short8*)&tile[kk][jb];
        *(short8*)(Wb + (size_t)i * 16384 + ((size_t)(c * 4 + nb) * 64 + l) * 8) = v;
    }
}

// ---------------------------------------------------------------------------
// scm_main: single-wave self-timed sequential SCM.
// Block = 1 wave = 64 threads owning 16 batch rows x all 64 hidden.
// B row stream: global_load_lds into private 2x32KB LDS double buffer,
// issued one step ahead; per-wave `s_waitcnt vmcnt(0)` (raw asm, NO barrier)
// at each step top is the completion wait — nothing block-wide ever drains.
// z history in registers: af[7] frozen chunks + ain in-progress (1 bf16
// element inserted per step). Scalar params prefetched one step ahead.
// grid: B/16 = 512, block 64 (2 blocks/CU: 2*64KB LDS)
// ---------------------------------------------------------------------------
__global__ __launch_bounds__(64, 1) void scm_main(const unsigned short* __restrict__ Wb,
                                                  const float* __restrict__ b1,
                                                  const float* __restrict__ W2,
                                                  const float* __restrict__ b2,
                                                  const float* __restrict__ ls,
                                                  const float* __restrict__ noise,
                                                  float* __restrict__ out) {
    __shared__ unsigned short bbuf[2][16384];   // 2 x 32KB private double buffer
    const int l = threadIdx.x;
    const int n = l & 15, q = l >> 4;
    const int rowbase = blockIdx.x * 16;
    const unsigned char* wbb = (const unsigned char*)Wb + (size_t)l * 16;
    unsigned char* bb0 = (unsigned char*)&bbuf[0][0];
    unsigned char* bb1 = (unsigned char*)&bbuf[1][0];

    short8 af[7];
    short8 ain = (short8)0;
#pragma unroll
    for (int c = 0; c < 7; ++c) af[c] = (short8)0;

    // 1-step-ahead scalar prefetch regs
    float b1p[4], w2p[4], nzp, b2pv, lspv;
#pragma unroll
    for (int nb = 0; nb < 4; ++nb) { b1p[nb] = b1[nb * 16 + n]; w2p[nb] = W2[nb * 16 + n]; }
    nzp  = noise[(size_t)(rowbase + n) * Dn];
    b2pv = b2[0];
    lspv = ls[0];
    // DMA step 0 (chunk 0) into slot 0
#pragma unroll
    for (int nb = 0; nb < 4; ++nb)
        dma16(wbb + (size_t)nb * 1024, bb0 + nb * 1024);

#pragma unroll 1
    for (int sec = 0; sec < 8; ++sec) {
        // promote the chunk completed by the previous section
#pragma unroll
        for (int k2 = 0; k2 < 7; ++k2)
            if (sec == k2 + 1) af[k2] = ain;
        if (sec > 0) ain = (short8)0;

#pragma unroll 1
        for (int o = 0; o < 4; ++o) {
            float zo[8];
#pragma unroll
            for (int e8 = 0; e8 < 8; ++e8) {
                const int i = sec * 32 + o * 8 + e8;

                // per-wave drain: DMA(i) + scalars(i) arrived (issued ~1 body ago)
                asm volatile("s_waitcnt vmcnt(0)" ::: "memory");

                // consume prefetched step-i params
                float b1c[4], w2c[4];
#pragma unroll
                for (int nb = 0; nb < 4; ++nb) { b1c[nb] = b1p[nb]; w2c[nb] = w2p[nb]; }
                float nzc = nzp, b2c = b2pv, lsc = lspv;

                // issue scalars(i+1), then DMA(i+1) into the other slot
                {
                    int ip = i + 1; if (ip > 255) ip = 255;
#pragma unroll
                    for (int nb = 0; nb < 4; ++nb) {
                        b1p[nb] = b1[ip * Hn + nb * 16 + n];
                        w2p[nb] = W2[ip * Hn + nb * 16 + n];
                    }
                    nzp  = noise[(size_t)(rowbase + n) * Dn + ip];
                    b2pv = b2[ip];
                    lspv = ls[ip];
                    const int cmax = ip >> 5;
                    unsigned char* dst = (e8 & 1) ? bb0 : bb1;   // slot (i+1)&1
                    const unsigned char* src = wbb + (size_t)ip * 32768;
#pragma unroll
                    for (int c = 0; c < 8; ++c)
                        if (c <= cmax) {
#pragma unroll
                            for (int nb = 0; nb < 4; ++nb)
                                dma16(src + (size_t)(c * 4 + nb) * 1024,
                                      dst + (c * 4 + nb) * 1024);
                        }
                }

                // MFMA from slot i&1: frozen chunks (af) + in-progress (ain)
                const unsigned char* lb = ((e8 & 1) ? bb1 : bb0) + (size_t)l * 16;
                floatx4 zero4 = {0.f, 0.f, 0.f, 0.f};
                floatx4 acc[4];
#pragma unroll
                for (int nb = 0; nb < 4; ++nb) acc[nb] = zero4;
#pragma unroll
                for (int c = 0; c < 7; ++c)
                    if (c < sec) {
#pragma unroll
                        for (int nb = 0; nb < 4; ++nb) {
                            short8 bfr = *(const short8*)(lb + (size_t)(c * 4 + nb) * 1024);
                            acc[nb] = __builtin_amdgcn_mfma_f32_16x16x32_bf16(af[c], bfr, acc[nb], 0, 0, 0);
                        }
                    }
#pragma unroll
                for (int nb = 0; nb < 4; ++nb) {
                    short8 bfr = *(const short8*)(lb + (size_t)(sec * 4 + nb) * 1024);
                    acc[nb] = __builtin_amdgcn_mfma_f32_16x16x32_bf16(ain, bfr, acc[nb], 0, 0, 0);
                }

                // epilogue: silu(h) . W2 over all 64 hidden
                float d[4];
#pragma unroll
                for (int r = 0; r < 4; ++r) {
                    float s = 0.f;
#pragma unroll
                    for (int nb = 0; nb < 4; ++nb) {
                        float h = acc[nb][r] + b1c[nb];
                        s += __fdividef(h, 1.f + __expf(-h)) * w2c[nb];
                    }
                    d[r] = s;
                }
#pragma unroll
                for (int m = 1; m <= 8; m <<= 1) {
#pragma unroll
                    for (int r = 0; r < 4; ++r) d[r] += __shfl_xor(d[r], m);
                }
                float z[4];
#pragma unroll
                for (int r = 0; r < 4; ++r) z[r] = d[r] + b2c;

                // zrow = z of row n, then add noise term
                int srcl = ((l & 15) >> 2) << 4;
                float t0 = __shfl(z[0], srcl), t1 = __shfl(z[1], srcl);
                float t2 = __shfl(z[2], srcl), t3 = __shfl(z[3], srcl);
                float za = (l & 1) ? t1 : t0;
                float zb = (l & 1) ? t3 : t2;
                float zrow = (l & 2) ? zb : za;
                zrow += __expf(lsc) * nzc;

                // insert bf16(zrow) into ain at element e8 (owner quad o)
                unsigned short zb16 = f2bf(zrow);
                ain[e8] = (q == o) ? (short)zb16 : ain[e8];
                zo[e8] = zrow;
            }
            // store 8 columns: lane (n,q) writes cols q*2, q*2+1
            float lo = (q == 0) ? zo[0] : (q == 1) ? zo[2] : (q == 2) ? zo[4] : zo[6];
            float hi = (q == 0) ? zo[1] : (q == 1) ? zo[3] : (q == 2) ? zo[5] : zo[7];
            *(float2*)(out + (size_t)(rowbase + n) * Dn + sec * 32 + o * 8 + q * 2) =
                make_float2(lo, hi);
        }
    }
}

// ---------------------------------------------------------------------------
extern "C" void kernel_launch(void* const* d_in, const int* in_sizes, int n_in,
                              void* d_out, int out_size, void* d_ws, size_t ws_size,
                              hipStream_t stream) {
    const float* noise      = (const float*)d_in[0];
    const float* adj_logits = (const float*)d_in[1];
    const float* W1         = (const float*)d_in[2];
    const float* b1         = (const float*)d_in[3];
    const float* W2         = (const float*)d_in[4];
    const float* b2         = (const float*)d_in[5];
    const float* log_sigma  = (const float*)d_in[6];
    float* out = (float*)d_out;

    const int B = in_sizes[0] / Dn;                 // 8192
    unsigned short* Wb = (unsigned short*)d_ws;     // 8.39 MB fragment weights

    prep_wb<<<dim3(Dn), 256, 0, stream>>>(W1, adj_logits, Wb);
    scm_main<<<dim3(B / 16), 64, 0, stream>>>(Wb, b1, W2, b2, log_sigma, noise, out);
}